// Round 2
// baseline (273.855 us; speedup 1.0000x reference)
//
#include <hip/hip_runtime.h>

// Masked 3x3 conv as implicit GEMM over GATHERED pixels (mask==1 only).
//   C[f][p] = sum_{tap,c} Wt[f][tap*512+c] * Xt[(h_p+dh)*194+(w_p+dw)][c]
//   out = bias everywhere (bias_fill), then out[f][pix(p)] = C[f][p]+bias[f].
// Round 6: ATTRIBUTION ROUND. prep_all split into 3 identically-bodied
// kernels (prep_x / prep_misc / bias_fill) so rocprof reports per-section
// durations. conv_gemm + compact byte-identical (control). Branch points:
//   prep_x >= 70us  -> restructure prep_x next round
//   prep sum <= 50us -> gap is dispatch overhead; reduce dispatch count next

typedef unsigned short ushort_t;
typedef __attribute__((ext_vector_type(8))) __bf16 bf16x8;
typedef __attribute__((ext_vector_type(4))) float f32x4;
typedef __attribute__((ext_vector_type(8))) unsigned short ushort8;

#define IMG_W 192
#define IMG_H 192
#define HW    36864       // 192*192
#define PAD_W 194
#define C_IN  512
#define F_OUT 512
#define KTOT  4608        // 9*512

__device__ __forceinline__ unsigned short f2bf(float f) {
  unsigned int u = __builtin_bit_cast(unsigned int, f);
  u += 0x7fffu + ((u >> 16) & 1u);
  return (unsigned short)(u >> 16);
}

__device__ __forceinline__ void async16(const void* g, void* l) {
  // 16B/lane global->LDS DMA; LDS dest is wave-uniform base + lane*16
  __builtin_amdgcn_global_load_lds(
      (const __attribute__((address_space(1))) unsigned int*)g,
      (__attribute__((address_space(3))) unsigned int*)l, 16, 0, 0);
}

// ============ prep_x: x NCHW fp32 -> padded NHWC bf16 interior =============
// 4608 blocks; 64c x 64w LDS transpose per block. Body identical to R5.
__global__ void prep_x(const float* __restrict__ x, ushort_t* __restrict__ Xt) {
  __shared__ float tile[64][65];
  const int bid = blockIdx.x;
  const int tid = threadIdx.x;

  const int p  = bid;
  const int w0 = (p % 3) * 64;
  const int c0 = ((p / 3) & 7) * 64;
  const int h  = p / 24;

  const int wl_r = tid & 63;
  const int cg_r = tid >> 6;
  const float* src = x + (size_t)(c0 + cg_r * 16) * HW + (size_t)h * IMG_W + w0 + wl_r;
#pragma unroll
  for (int cc = 0; cc < 16; ++cc)
    tile[cg_r * 16 + cc][wl_r] = src[(size_t)cc * HW];
  __syncthreads();

  const int wl = tid >> 2;
  const int cg = tid & 3;
  ushort_t* dst = Xt + ((size_t)(h + 1) * PAD_W + (w0 + wl + 1)) * C_IN + c0 + cg * 16;
  ushort8 v0, v1;
#pragma unroll
  for (int cc = 0; cc < 8; ++cc) v0[cc] = f2bf(tile[cg * 16 + cc][wl]);
#pragma unroll
  for (int cc = 0; cc < 8; ++cc) v1[cc] = f2bf(tile[cg * 16 + 8 + cc][wl]);
  *(ushort8*)dst = v0;
  *(ushort8*)(dst + 8) = v1;
}

// ============ prep_misc: halo_zero + prep_w + counter reset ================
// blocks [0,193):    halo_zero (772 border pixels of Xt, 16B/thread)
// blocks [193,1217): prep_w  (w [f][c][3][3] -> Wt [f][tap*512+c])
// block  1217:       zero compaction counter
__global__ void prep_misc(const float* __restrict__ w, ushort_t* __restrict__ Wt,
                          ushort_t* __restrict__ Xt, int* __restrict__ counter) {
  const int bid = blockIdx.x;
  const int tid = threadIdx.x;

  if (bid < 193) {
    // ---- halo_zero ---- 772 border pixels x 1KB, 16B per thread
    const int idx = bid * 256 + tid;            // 49408 = 772*64 stores
    const int p   = idx >> 6;                   // halo pixel 0..771
    const int off = (idx & 63) * 8;             // ushort offset (16B chunks)
    int r, c;
    if (p < 388) { r = (p >= 194) ? 193 : 0; c = (p >= 194) ? p - 194 : p; }
    else         { int q = p - 388; r = 1 + (q >> 1); c = (q & 1) ? 193 : 0; }
    ushort8 z = {0, 0, 0, 0, 0, 0, 0, 0};
    *(ushort8*)(Xt + ((size_t)r * PAD_W + c) * C_IN + off) = z;
  } else if (bid < 1217) {
    // ---- prep_w ----
    const int idx = (bid - 193) * 256 + tid;    // f*512 + c
    const int f = idx >> 9;
    const int c = idx & 511;
    const float* src = w + (size_t)idx * 9;
    float v[9];
#pragma unroll
    for (int t = 0; t < 9; ++t) v[t] = src[t];
    ushort_t* dst = Wt + (size_t)f * KTOT + c;
#pragma unroll
    for (int t = 0; t < 9; ++t) dst[t * C_IN] = f2bf(v[t]);
  } else {
    if (tid == 0) *counter = 0;
  }
}

// ============ bias_fill: out[f][*] = bias[f], grid-stride float4 ===========
__global__ void bias_fill(const float* __restrict__ bias, float* __restrict__ out) {
  // 4,718,592 float4 lines total = 2048 blocks * 256 threads * 9 iters
  const int g = blockIdx.x * 256 + threadIdx.x; // [0, 524288)
  f32x4* o4 = (f32x4*)out;
#pragma unroll
  for (int it = 0; it < 9; ++it) {
    const int n4 = g + it * 524288;
    const int f  = n4 / (HW / 4);               // 9216 float4 per filter
    const float bv = bias[f];
    f32x4 v = {bv, bv, bv, bv};
    o4[n4] = v;
  }
}

// ---------------- compact: pixel ids where mask==1 (wave-aggregated) -------
__global__ void compact(const int* __restrict__ mask, int* __restrict__ list,
                        int* __restrict__ counter) {
  const int i = blockIdx.x * 256 + threadIdx.x;
  const int lane = threadIdx.x & 63;
  const int m = mask[i];
  unsigned long long b = __ballot(m != 0);
  int base = 0;
  if (lane == 0 && b) base = atomicAdd(counter, __popcll(b));
  base = __shfl(base, 0);
  if (m) list[base + __popcll(b & ((1ull << lane) - 1ull))] = i;
}

// ---------------- implicit GEMM over gathered pixels, BK=64 ----------------
__global__ __launch_bounds__(256, 3) void conv_gemm(
    const ushort_t* __restrict__ Wt, const ushort_t* __restrict__ Xt,
    const float* __restrict__ bias, const int* __restrict__ list,
    const int* __restrict__ counter, float* __restrict__ out) {
  __shared__ __align__(16) ushort_t As[128 * 64];  // [m 0..127][k 0..63], swizzled
  __shared__ __align__(16) ushort_t Bs[128 * 64];  // [p 0..127][k 0..63], swizzled

  const int count = counter[0];
  const int n0 = blockIdx.x * 128;
  if (n0 >= count) return;

  const int tid  = threadIdx.x;
  const int lane = tid & 63;
  const int wave = tid >> 6;
  const int wm   = wave >> 1;
  const int wn   = wave & 1;
  const int m0   = blockIdx.y * 128;

  // ---- staging role: wave w stages rows [w*32, w*32+32) of A and B, via
  // 4 issues of 1KB (8 rows each). lane -> (row_rel = lane>>3, phys = lane&7).
  // Swizzle: phys slot p at row r holds logical chunk p ^ (r&7); here
  // r&7 == lane>>3, so each lane's logical chunk q is loop-invariant.
  const int rrel = lane >> 3;
  const int q    = (lane & 7) ^ rrel;

  const ushort_t* aSrc = Wt + (size_t)(m0 + wave * 32 + rrel) * KTOT + q * 8;

  unsigned int bOffs[4];
#pragma unroll
  for (int ii = 0; ii < 4; ++ii) {
    const int pos = n0 + wave * 32 + ii * 8 + rrel;
    const int pix = (pos < count) ? list[pos] : 0;
    const int hh = pix / IMG_W, ww = pix - hh * IMG_W;
    bOffs[ii] = ((hh + 1) * PAD_W + (ww + 1)) * C_IN + q * 8;
  }

  ushort_t* aDst = &As[wave * 32 * 64];  // + ii*512 per issue (8 rows x 64)
  ushort_t* bDst = &Bs[wave * 32 * 64];

  const int col  = lane & 15;
  const int quad = lane >> 4;

  f32x4 acc[4][4] = {};

  // initial staging (kk=0: tap 0, kc 0)
  {
    const int toff0 = -(PAD_W + 1) * C_IN;
#pragma unroll
    for (int ii = 0; ii < 4; ++ii) {
      async16(aSrc + (size_t)ii * 8 * KTOT, aDst + ii * 512);
      async16(Xt + (int)bOffs[ii] + toff0, bDst + ii * 512);
    }
  }

#pragma unroll 1
  for (int kk = 0; kk < 72; ++kk) {
    __syncthreads();   // staging for kk ready (drains vmcnt; DMA was in
                       // flight during the previous chunk's MFMA burst)
    bf16x8 af[2][4], bfr[2][4];
#pragma unroll
    for (int s = 0; s < 2; ++s) {
#pragma unroll
      for (int i = 0; i < 4; ++i) {
        const int row = wm * 64 + i * 16 + col;
        af[s][i] = *(const bf16x8*)&As[row * 64 + ((s * 4 + quad) ^ (row & 7)) * 8];
      }
#pragma unroll
      for (int j = 0; j < 4; ++j) {
        const int row = wn * 64 + j * 16 + col;
        bfr[s][j] = *(const bf16x8*)&Bs[row * 64 + ((s * 4 + quad) ^ (row & 7)) * 8];
      }
    }
    if (kk < 71) {
      __syncthreads();   // all waves done reading LDS; safe to overwrite
      const int kn   = kk + 1;
      const int tapn = kn >> 3;
      const int kcn  = (kn & 7) * 64;
      const int toffn = ((tapn / 3) * PAD_W + (tapn % 3) - (PAD_W + 1)) * C_IN;
      const int aoffn = tapn * 512 + kcn;
#pragma unroll
      for (int ii = 0; ii < 4; ++ii) {
        async16(aSrc + (size_t)ii * 8 * KTOT + aoffn, aDst + ii * 512);
        async16(Xt + (int)bOffs[ii] + toffn + kcn, bDst + ii * 512);
      }
    }
#pragma unroll
    for (int s = 0; s < 2; ++s)
#pragma unroll
      for (int i = 0; i < 4; ++i)
#pragma unroll
        for (int j = 0; j < 4; ++j)
          acc[i][j] = __builtin_amdgcn_mfma_f32_16x16x32_bf16(af[s][i], bfr[s][j],
                                                              acc[i][j], 0, 0, 0);
  }

  // epilogue: out[mrow][pix] = acc + bias   (C/D: col=lane&15, row=quad*4+r)
#pragma unroll
  for (int j = 0; j < 4; ++j) {
    const int pos = n0 + wn * 64 + j * 16 + col;
    if (pos < count) {
      const int n_pix = list[pos];
#pragma unroll
      for (int i = 0; i < 4; ++i) {
        const int mrow = m0 + wm * 64 + i * 16 + quad * 4;
        float* o = out + (size_t)mrow * HW + n_pix;
#pragma unroll
        for (int r = 0; r < 4; ++r)
          o[(size_t)r * HW] = acc[i][j][r] + bias[mrow + r];
      }
    }
  }
}

extern "C" void kernel_launch(void* const* d_in, const int* in_sizes, int n_in,
                              void* d_out, int out_size, void* d_ws, size_t ws_size,
                              hipStream_t stream) {
  const float* x    = (const float*)d_in[0];  // [512][192][192]
  const float* w    = (const float*)d_in[1];  // [512][512][3][3]
  const float* bias = (const float*)d_in[2];  // [512]
  const int*   mask = (const int*)d_in[3];    // [192][192]
  float* out = (float*)d_out;                 // [512][192][192]

  // ws layout: list (36864 int) | counter | pad | Xt (38.5MB) | Wt (4.7MB)
  int* list    = (int*)d_ws;
  int* counter = list + HW;
  ushort_t* Xt = (ushort_t*)((char*)d_ws + 147712);   // 16B-aligned
  ushort_t* Wt = Xt + (size_t)PAD_W * PAD_W * C_IN;

  prep_x<<<dim3(4608), 256, 0, stream>>>(x, Xt);
  prep_misc<<<dim3(1218), 256, 0, stream>>>(w, Wt, Xt, counter);
  bias_fill<<<dim3(2048), 256, 0, stream>>>(bias, out);
  compact<<<dim3(HW / 256), 256, 0, stream>>>(mask, list, counter);
  conv_gemm<<<dim3((HW + 127) / 128, F_OUT / 128), 256, 0, stream>>>(
      Wt, Xt, bias, list, counter, out);
}

// Round 3
// 265.179 us; speedup vs baseline: 1.0327x; 1.0327x over previous
//
#include <hip/hip_runtime.h>

// Masked 3x3 conv as implicit GEMM over GATHERED pixels (mask==1 only).
//   C[f][p] = sum_{tap,c} Wt[f][tap*512+c] * Xt[(h_p+dh)*194+(w_p+dw)][c]
//   out = bias everywhere (prep_all), then out[f][pix(p)] = C[f][p]+bias[f].
// Round 7: kill same-address atomic serialization in compact. Old compact:
// 576 atomicAdds (144 blocks x 4 waves) on ONE word -> cross-XCD ping-pong,
// ~150ns each ~= 86us (matches the unexplained gap in the BW accounting).
// New: deterministic 2-phase compact (count -> prefix+scatter), ZERO
// same-address atomics. prep re-fused (R1 bodies). conv_gemm unchanged.

typedef unsigned short ushort_t;
typedef __attribute__((ext_vector_type(8))) __bf16 bf16x8;
typedef __attribute__((ext_vector_type(4))) float f32x4;
typedef __attribute__((ext_vector_type(8))) unsigned short ushort8;

#define IMG_W 192
#define IMG_H 192
#define HW    36864       // 192*192
#define PAD_W 194
#define C_IN  512
#define F_OUT 512
#define KTOT  4608        // 9*512
#define NCBLK 144         // compact blocks (256 px each)

__device__ __forceinline__ unsigned short f2bf(float f) {
  unsigned int u = __builtin_bit_cast(unsigned int, f);
  u += 0x7fffu + ((u >> 16) & 1u);
  return (unsigned short)(u >> 16);
}

__device__ __forceinline__ void async16(const void* g, void* l) {
  // 16B/lane global->LDS DMA; LDS dest is wave-uniform base + lane*16
  __builtin_amdgcn_global_load_lds(
      (const __attribute__((address_space(1))) unsigned int*)g,
      (__attribute__((address_space(3))) unsigned int*)l, 16, 0, 0);
}

// ============ prep_all: fused independent prep (1 dispatch) ============
// blocks [0,4608):      prep_x  (x NCHW fp32 -> padded NHWC bf16 interior)
// blocks [4608,4801):   halo_zero (772 border pixels of Xt, 16B/thread)
// blocks [4801,5825):   prep_w  (w [f][c][3][3] -> Wt [f][tap*512+c])
// block  5825:          (spare; counter now written by compact_scatter)
// blocks [5826,7874):   bias broadcast: grid-stride, 9 float4/thread
__global__ void prep_all(const float* __restrict__ x, const float* __restrict__ w,
                         const float* __restrict__ bias,
                         ushort_t* __restrict__ Xt, ushort_t* __restrict__ Wt,
                         int* __restrict__ counter, float* __restrict__ out) {
  __shared__ float tile[64][65];
  const int bid = blockIdx.x;
  const int tid = threadIdx.x;

  if (bid < 4608) {
    // ---- prep_x ---- (unchanged; 64c x 64w LDS transpose)
    const int p  = bid;
    const int w0 = (p % 3) * 64;
    const int c0 = ((p / 3) & 7) * 64;
    const int h  = p / 24;

    const int wl_r = tid & 63;
    const int cg_r = tid >> 6;
    const float* src = x + (size_t)(c0 + cg_r * 16) * HW + (size_t)h * IMG_W + w0 + wl_r;
#pragma unroll
    for (int cc = 0; cc < 16; ++cc)
      tile[cg_r * 16 + cc][wl_r] = src[(size_t)cc * HW];
    __syncthreads();

    const int wl = tid >> 2;
    const int cg = tid & 3;
    ushort_t* dst = Xt + ((size_t)(h + 1) * PAD_W + (w0 + wl + 1)) * C_IN + c0 + cg * 16;
    ushort8 v0, v1;
#pragma unroll
    for (int cc = 0; cc < 8; ++cc) v0[cc] = f2bf(tile[cg * 16 + cc][wl]);
#pragma unroll
    for (int cc = 0; cc < 8; ++cc) v1[cc] = f2bf(tile[cg * 16 + 8 + cc][wl]);
    *(ushort8*)dst = v0;
    *(ushort8*)(dst + 8) = v1;
  } else if (bid < 4801) {
    // ---- halo_zero ---- 772 border pixels x 1KB, 16B per thread
    const int idx = (bid - 4608) * 256 + tid;   // 49408 = 772*64 stores
    const int p   = idx >> 6;                   // halo pixel 0..771
    const int off = (idx & 63) * 8;             // ushort offset (16B chunks)
    int r, c;
    if (p < 388) { r = (p >= 194) ? 193 : 0; c = (p >= 194) ? p - 194 : p; }
    else         { int q = p - 388; r = 1 + (q >> 1); c = (q & 1) ? 193 : 0; }
    ushort8 z = {0, 0, 0, 0, 0, 0, 0, 0};
    *(ushort8*)(Xt + ((size_t)r * PAD_W + c) * C_IN + off) = z;
  } else if (bid < 5825) {
    // ---- prep_w ----
    const int idx = (bid - 4801) * 256 + tid;   // f*512 + c
    const int f = idx >> 9;
    const int c = idx & 511;
    const float* src = w + (size_t)idx * 9;
    float v[9];
#pragma unroll
    for (int t = 0; t < 9; ++t) v[t] = src[t];
    ushort_t* dst = Wt + (size_t)f * KTOT + c;
#pragma unroll
    for (int t = 0; t < 9; ++t) dst[t * C_IN] = f2bf(v[t]);
  } else if (bid == 5825) {
    // spare (kept so bias block numbering matches R1 exactly)
  } else {
    // ---- bias broadcast: grid-stride, coalesced float4 ----
    // 4,718,592 float4 lines total = 2048 blocks * 256 threads * 9 iters
    const int g = (bid - 5826) * 256 + tid;     // [0, 524288)
    f32x4* o4 = (f32x4*)out;
#pragma unroll
    for (int it = 0; it < 9; ++it) {
      const int n4 = g + it * 524288;
      const int f  = n4 / (HW / 4);             // 9216 float4 per filter
      const float bv = bias[f];
      f32x4 v = {bv, bv, bv, bv};
      o4[n4] = v;
    }
  }
}

// ---- compact phase 1: per-block masked-pixel counts (no atomics) ----------
__global__ void compact_count(const int* __restrict__ mask,
                              int* __restrict__ counts) {
  __shared__ int wcnt[4];
  const int i = blockIdx.x * 256 + threadIdx.x;
  const int lane = threadIdx.x & 63;
  const int wave = threadIdx.x >> 6;
  unsigned long long b = __ballot(mask[i] != 0);
  if (lane == 0) wcnt[wave] = __popcll(b);
  __syncthreads();
  if (threadIdx.x == 0)
    counts[blockIdx.x] = wcnt[0] + wcnt[1] + wcnt[2] + wcnt[3];
}

// ---- compact phase 2: deterministic prefix + scatter (no atomics) ---------
__global__ void compact_scatter(const int* __restrict__ mask,
                                const int* __restrict__ counts,
                                int* __restrict__ list, int* __restrict__ counter) {
  __shared__ int woff[4];
  const int bid  = blockIdx.x;
  const int tid  = threadIdx.x;
  const int lane = tid & 63;
  const int wave = tid >> 6;
  const int i = bid * 256 + tid;
  const int m = mask[i];
  unsigned long long b = __ballot(m != 0);
  if (lane == 0) woff[wave] = __popcll(b);
  __syncthreads();
  if (tid == 0) {
    int acc = 0;                                 // exclusive prefix over blocks
    for (int k = 0; k < bid; ++k) acc += counts[k];  // 576B, L2-hot
    const int c0 = woff[0], c1 = woff[1], c2 = woff[2], c3 = woff[3];
    woff[0] = acc; woff[1] = acc + c0; woff[2] = acc + c0 + c1;
    woff[3] = acc + c0 + c1 + c2;
    if (bid == NCBLK - 1) counter[0] = acc + c0 + c1 + c2 + c3;  // total
  }
  __syncthreads();
  if (m) list[woff[wave] + __popcll(b & ((1ull << lane) - 1ull))] = i;
}

// ---------------- implicit GEMM over gathered pixels, BK=64 ----------------
__global__ __launch_bounds__(256, 3) void conv_gemm(
    const ushort_t* __restrict__ Wt, const ushort_t* __restrict__ Xt,
    const float* __restrict__ bias, const int* __restrict__ list,
    const int* __restrict__ counter, float* __restrict__ out) {
  __shared__ __align__(16) ushort_t As[128 * 64];  // [m 0..127][k 0..63], swizzled
  __shared__ __align__(16) ushort_t Bs[128 * 64];  // [p 0..127][k 0..63], swizzled

  const int count = counter[0];
  const int n0 = blockIdx.x * 128;
  if (n0 >= count) return;

  const int tid  = threadIdx.x;
  const int lane = tid & 63;
  const int wave = tid >> 6;
  const int wm   = wave >> 1;
  const int wn   = wave & 1;
  const int m0   = blockIdx.y * 128;

  // ---- staging role: wave w stages rows [w*32, w*32+32) of A and B, via
  // 4 issues of 1KB (8 rows each). lane -> (row_rel = lane>>3, phys = lane&7).
  // Swizzle: phys slot p at row r holds logical chunk p ^ (r&7); here
  // r&7 == lane>>3, so each lane's logical chunk q is loop-invariant.
  const int rrel = lane >> 3;
  const int q    = (lane & 7) ^ rrel;

  const ushort_t* aSrc = Wt + (size_t)(m0 + wave * 32 + rrel) * KTOT + q * 8;

  unsigned int bOffs[4];
#pragma unroll
  for (int ii = 0; ii < 4; ++ii) {
    const int pos = n0 + wave * 32 + ii * 8 + rrel;
    const int pix = (pos < count) ? list[pos] : 0;
    const int hh = pix / IMG_W, ww = pix - hh * IMG_W;
    bOffs[ii] = ((hh + 1) * PAD_W + (ww + 1)) * C_IN + q * 8;
  }

  ushort_t* aDst = &As[wave * 32 * 64];  // + ii*512 per issue (8 rows x 64)
  ushort_t* bDst = &Bs[wave * 32 * 64];

  const int col  = lane & 15;
  const int quad = lane >> 4;

  f32x4 acc[4][4] = {};

  // initial staging (kk=0: tap 0, kc 0)
  {
    const int toff0 = -(PAD_W + 1) * C_IN;
#pragma unroll
    for (int ii = 0; ii < 4; ++ii) {
      async16(aSrc + (size_t)ii * 8 * KTOT, aDst + ii * 512);
      async16(Xt + (int)bOffs[ii] + toff0, bDst + ii * 512);
    }
  }

#pragma unroll 1
  for (int kk = 0; kk < 72; ++kk) {
    __syncthreads();   // staging for kk ready (drains vmcnt; DMA was in
                       // flight during the previous chunk's MFMA burst)
    bf16x8 af[2][4], bfr[2][4];
#pragma unroll
    for (int s = 0; s < 2; ++s) {
#pragma unroll
      for (int i = 0; i < 4; ++i) {
        const int row = wm * 64 + i * 16 + col;
        af[s][i] = *(const bf16x8*)&As[row * 64 + ((s * 4 + quad) ^ (row & 7)) * 8];
      }
#pragma unroll
      for (int j = 0; j < 4; ++j) {
        const int row = wn * 64 + j * 16 + col;
        bfr[s][j] = *(const bf16x8*)&Bs[row * 64 + ((s * 4 + quad) ^ (row & 7)) * 8];
      }
    }
    if (kk < 71) {
      __syncthreads();   // all waves done reading LDS; safe to overwrite
      const int kn   = kk + 1;
      const int tapn = kn >> 3;
      const int kcn  = (kn & 7) * 64;
      const int toffn = ((tapn / 3) * PAD_W + (tapn % 3) - (PAD_W + 1)) * C_IN;
      const int aoffn = tapn * 512 + kcn;
#pragma unroll
      for (int ii = 0; ii < 4; ++ii) {
        async16(aSrc + (size_t)ii * 8 * KTOT + aoffn, aDst + ii * 512);
        async16(Xt + (int)bOffs[ii] + toffn + kcn, bDst + ii * 512);
      }
    }
#pragma unroll
    for (int s = 0; s < 2; ++s)
#pragma unroll
      for (int i = 0; i < 4; ++i)
#pragma unroll
        for (int j = 0; j < 4; ++j)
          acc[i][j] = __builtin_amdgcn_mfma_f32_16x16x32_bf16(af[s][i], bfr[s][j],
                                                              acc[i][j], 0, 0, 0);
  }

  // epilogue: out[mrow][pix] = acc + bias   (C/D: col=lane&15, row=quad*4+r)
#pragma unroll
  for (int j = 0; j < 4; ++j) {
    const int pos = n0 + wn * 64 + j * 16 + col;
    if (pos < count) {
      const int n_pix = list[pos];
#pragma unroll
      for (int i = 0; i < 4; ++i) {
        const int mrow = m0 + wm * 64 + i * 16 + quad * 4;
        float* o = out + (size_t)mrow * HW + n_pix;
#pragma unroll
        for (int r = 0; r < 4; ++r)
          o[(size_t)r * HW] = acc[i][j][r] + bias[mrow + r];
      }
    }
  }
}

extern "C" void kernel_launch(void* const* d_in, const int* in_sizes, int n_in,
                              void* d_out, int out_size, void* d_ws, size_t ws_size,
                              hipStream_t stream) {
  const float* x    = (const float*)d_in[0];  // [512][192][192]
  const float* w    = (const float*)d_in[1];  // [512][512][3][3]
  const float* bias = (const float*)d_in[2];  // [512]
  const int*   mask = (const int*)d_in[3];    // [192][192]
  float* out = (float*)d_out;                 // [512][192][192]

  // ws layout: list (36864 int) | counter | counts[144] | pad | Xt | Wt
  int* list    = (int*)d_ws;
  int* counter = list + HW;
  int* counts  = counter + 1;
  ushort_t* Xt = (ushort_t*)((char*)d_ws + 148096);   // 128B-aligned
  ushort_t* Wt = Xt + (size_t)PAD_W * PAD_W * C_IN;

  prep_all<<<dim3(7874), 256, 0, stream>>>(x, w, bias, Xt, Wt, counter, out);
  compact_count<<<dim3(NCBLK), 256, 0, stream>>>(mask, counts);
  compact_scatter<<<dim3(NCBLK), 256, 0, stream>>>(mask, counts, list, counter);
  conv_gemm<<<dim3((HW + 127) / 128, F_OUT / 128), 256, 0, stream>>>(
      Wt, Xt, bias, list, counter, out);
}

// Round 4
// 262.975 us; speedup vs baseline: 1.0414x; 1.0084x over previous
//
#include <hip/hip_runtime.h>

// Masked 3x3 conv as implicit GEMM over GATHERED pixels (mask==1 only).
//   C[f][p] = sum_{tap,c} Wt[f][tap*512+c] * Xt[(h_p+dh)*194+(w_p+dw)][c]
//   out = conv*mask + b  ==  bias everywhere, conv+bias at masked pixels.
// Round 8: fold the bias broadcast INTO conv_gemm. list is sorted, so each
// n-block owns the contiguous pixel span [list[n0-1]+1, list[n0+127]+1);
// spans partition [0,HW). Each block dense-fills its span x its 128 rows
// with bias (2 rows per K-iter, hidden under MFMA; drained by the loop's
// own vmcnt(0)+barrier), then the epilogue scatter overwrites masked
// pixels in L2-resident fully-written lines. Kills bias_fill's 75.5MB
// write + conv's ~40MB RFO fetch + one dispatch. compact_count folded
// into prep_all (mask is input-only). 3 dispatches total.

typedef unsigned short ushort_t;
typedef __attribute__((ext_vector_type(8))) __bf16 bf16x8;
typedef __attribute__((ext_vector_type(4))) float f32x4;
typedef __attribute__((ext_vector_type(8))) unsigned short ushort8;

#define IMG_W 192
#define IMG_H 192
#define HW    36864       // 192*192
#define PAD_W 194
#define C_IN  512
#define F_OUT 512
#define KTOT  4608        // 9*512
#define NCBLK 144         // compact blocks (256 px each)

__device__ __forceinline__ unsigned short f2bf(float f) {
  unsigned int u = __builtin_bit_cast(unsigned int, f);
  u += 0x7fffu + ((u >> 16) & 1u);
  return (unsigned short)(u >> 16);
}

__device__ __forceinline__ void async16(const void* g, void* l) {
  // 16B/lane global->LDS DMA; LDS dest is wave-uniform base + lane*16
  __builtin_amdgcn_global_load_lds(
      (const __attribute__((address_space(1))) unsigned int*)g,
      (__attribute__((address_space(3))) unsigned int*)l, 16, 0, 0);
}

// ============ prep_all: fused independent prep (1 dispatch) ============
// blocks [0,4608):     prep_x  (x NCHW fp32 -> padded NHWC bf16 interior)
// blocks [4608,4801):  halo_zero (772 border pixels of Xt, 16B/thread)
// blocks [4801,5825):  prep_w  (w [f][c][3][3] -> Wt [f][tap*512+c])
// blocks [5825,5969):  compact_count (per-block masked-pixel counts)
__global__ void prep_all(const float* __restrict__ x, const float* __restrict__ w,
                         const int* __restrict__ mask,
                         ushort_t* __restrict__ Xt, ushort_t* __restrict__ Wt,
                         int* __restrict__ counts) {
  __shared__ float tile[64][65];
  __shared__ int wcnt[4];
  const int bid = blockIdx.x;
  const int tid = threadIdx.x;

  if (bid < 4608) {
    // ---- prep_x ---- (unchanged; 64c x 64w LDS transpose)
    const int p  = bid;
    const int w0 = (p % 3) * 64;
    const int c0 = ((p / 3) & 7) * 64;
    const int h  = p / 24;

    const int wl_r = tid & 63;
    const int cg_r = tid >> 6;
    const float* src = x + (size_t)(c0 + cg_r * 16) * HW + (size_t)h * IMG_W + w0 + wl_r;
#pragma unroll
    for (int cc = 0; cc < 16; ++cc)
      tile[cg_r * 16 + cc][wl_r] = src[(size_t)cc * HW];
    __syncthreads();

    const int wl = tid >> 2;
    const int cg = tid & 3;
    ushort_t* dst = Xt + ((size_t)(h + 1) * PAD_W + (w0 + wl + 1)) * C_IN + c0 + cg * 16;
    ushort8 v0, v1;
#pragma unroll
    for (int cc = 0; cc < 8; ++cc) v0[cc] = f2bf(tile[cg * 16 + cc][wl]);
#pragma unroll
    for (int cc = 0; cc < 8; ++cc) v1[cc] = f2bf(tile[cg * 16 + 8 + cc][wl]);
    *(ushort8*)dst = v0;
    *(ushort8*)(dst + 8) = v1;
  } else if (bid < 4801) {
    // ---- halo_zero ---- 772 border pixels x 1KB, 16B per thread
    const int idx = (bid - 4608) * 256 + tid;   // 49408 = 772*64 stores
    const int p   = idx >> 6;                   // halo pixel 0..771
    const int off = (idx & 63) * 8;             // ushort offset (16B chunks)
    int r, c;
    if (p < 388) { r = (p >= 194) ? 193 : 0; c = (p >= 194) ? p - 194 : p; }
    else         { int q = p - 388; r = 1 + (q >> 1); c = (q & 1) ? 193 : 0; }
    ushort8 z = {0, 0, 0, 0, 0, 0, 0, 0};
    *(ushort8*)(Xt + ((size_t)r * PAD_W + c) * C_IN + off) = z;
  } else if (bid < 5825) {
    // ---- prep_w ----
    const int idx = (bid - 4801) * 256 + tid;   // f*512 + c
    const int f = idx >> 9;
    const int c = idx & 511;
    const float* src = w + (size_t)idx * 9;
    float v[9];
#pragma unroll
    for (int t = 0; t < 9; ++t) v[t] = src[t];
    ushort_t* dst = Wt + (size_t)f * KTOT + c;
#pragma unroll
    for (int t = 0; t < 9; ++t) dst[t * C_IN] = f2bf(v[t]);
  } else {
    // ---- compact_count ---- (no atomics)
    const int cbid = bid - 5825;
    const int i = cbid * 256 + tid;
    const int lane = tid & 63;
    const int wave = tid >> 6;
    unsigned long long b = __ballot(mask[i] != 0);
    if (lane == 0) wcnt[wave] = __popcll(b);
    __syncthreads();
    if (tid == 0) counts[cbid] = wcnt[0] + wcnt[1] + wcnt[2] + wcnt[3];
  }
}

// ---- compact phase 2: deterministic prefix + scatter (no atomics) ---------
// list comes out globally SORTED ascending (blocks ordered, waves ordered,
// lanes ordered) -- conv_gemm's span ownership depends on this.
__global__ void compact_scatter(const int* __restrict__ mask,
                                const int* __restrict__ counts,
                                int* __restrict__ list, int* __restrict__ counter) {
  __shared__ int woff[4];
  const int bid  = blockIdx.x;
  const int tid  = threadIdx.x;
  const int lane = tid & 63;
  const int wave = tid >> 6;
  const int i = bid * 256 + tid;
  const int m = mask[i];
  unsigned long long b = __ballot(m != 0);
  if (lane == 0) woff[wave] = __popcll(b);
  __syncthreads();
  if (tid == 0) {
    int acc = 0;                                 // exclusive prefix over blocks
    for (int k = 0; k < bid; ++k) acc += counts[k];  // 576B, L2-hot
    const int c0 = woff[0], c1 = woff[1], c2 = woff[2], c3 = woff[3];
    woff[0] = acc; woff[1] = acc + c0; woff[2] = acc + c0 + c1;
    woff[3] = acc + c0 + c1 + c2;
    if (bid == NCBLK - 1) counter[0] = acc + c0 + c1 + c2 + c3;  // total
  }
  __syncthreads();
  if (m) list[woff[wave] + __popcll(b & ((1ull << lane) - 1ull))] = i;
}

// ---------------- implicit GEMM over gathered pixels, BK=64 ----------------
__global__ __launch_bounds__(256, 3) void conv_gemm(
    const ushort_t* __restrict__ Wt, const ushort_t* __restrict__ Xt,
    const float* __restrict__ bias, const int* __restrict__ list,
    const int* __restrict__ counter, float* __restrict__ out) {
  __shared__ __align__(16) ushort_t As[128 * 64];  // [m 0..127][k 0..63], swizzled
  __shared__ __align__(16) ushort_t Bs[128 * 64];  // [p 0..127][k 0..63], swizzled

  const int count = counter[0];
  const int n0 = blockIdx.x * 128;
  const int m0 = blockIdx.y * 128;
  const int tid  = threadIdx.x;

  // ---- pixel-span ownership (list sorted): spans partition [0, HW) ----
  int lo_pix, hi_pix;
  {
    const int loPos = n0, hiPos = n0 + 128;
    lo_pix = (loPos == 0) ? 0 : ((loPos <= count) ? list[loPos - 1] + 1 : HW);
    hi_pix = (hiPos <= count) ? list[hiPos - 1] + 1 : HW;
    if (hi_pix < lo_pix) hi_pix = lo_pix;
  }

  if (n0 >= count) {
    // inactive block: dense bias fill of owned span (tail / count==0 case)
    for (int rr = 0; rr < 128; ++rr) {
      const float bv = bias[m0 + rr];
      float* o = out + (size_t)(m0 + rr) * HW;
      for (int p = lo_pix + tid; p < hi_pix; p += 256) o[p] = bv;
    }
    return;
  }

  const int lane = tid & 63;
  const int wave = tid >> 6;
  const int wm   = wave >> 1;
  const int wn   = wave & 1;

  // ---- staging role: wave w stages rows [w*32, w*32+32) of A and B, via
  // 4 issues of 1KB (8 rows each). lane -> (row_rel = lane>>3, phys = lane&7).
  // Swizzle: phys slot p at row r holds logical chunk p ^ (r&7); here
  // r&7 == lane>>3, so each lane's logical chunk q is loop-invariant.
  const int rrel = lane >> 3;
  const int q    = (lane & 7) ^ rrel;

  const ushort_t* aSrc = Wt + (size_t)(m0 + wave * 32 + rrel) * KTOT + q * 8;

  unsigned int bOffs[4];
#pragma unroll
  for (int ii = 0; ii < 4; ++ii) {
    const int pos = n0 + wave * 32 + ii * 8 + rrel;
    const int pix = (pos < count) ? list[pos] : 0;
    const int hh = pix / IMG_W, ww = pix - hh * IMG_W;
    bOffs[ii] = ((hh + 1) * PAD_W + (ww + 1)) * C_IN + q * 8;
  }

  ushort_t* aDst = &As[wave * 32 * 64];  // + ii*512 per issue (8 rows x 64)
  ushort_t* bDst = &Bs[wave * 32 * 64];

  const int col  = lane & 15;
  const int quad = lane >> 4;

  f32x4 acc[4][4] = {};

  // initial staging (kk=0: tap 0, kc 0)
  {
    const int toff0 = -(PAD_W + 1) * C_IN;
#pragma unroll
    for (int ii = 0; ii < 4; ++ii) {
      async16(aSrc + (size_t)ii * 8 * KTOT, aDst + ii * 512);
      async16(Xt + (int)bOffs[ii] + toff0, bDst + ii * 512);
    }
  }

#pragma unroll 1
  for (int kk = 0; kk < 72; ++kk) {
    __syncthreads();   // staging for kk ready (drains vmcnt; DMA was in
                       // flight during the previous chunk's MFMA burst)
    bf16x8 af[2][4], bfr[2][4];
#pragma unroll
    for (int s = 0; s < 2; ++s) {
#pragma unroll
      for (int i = 0; i < 4; ++i) {
        const int row = wm * 64 + i * 16 + col;
        af[s][i] = *(const bf16x8*)&As[row * 64 + ((s * 4 + quad) ^ (row & 7)) * 8];
      }
#pragma unroll
      for (int j = 0; j < 4; ++j) {
        const int row = wn * 64 + j * 16 + col;
        bfr[s][j] = *(const bf16x8*)&Bs[row * 64 + ((s * 4 + quad) ^ (row & 7)) * 8];
      }
    }
    if (kk < 71) {
      __syncthreads();   // all waves done reading LDS; safe to overwrite
      const int kn   = kk + 1;
      const int tapn = kn >> 3;
      const int kcn  = (kn & 7) * 64;
      const int toffn = ((tapn / 3) * PAD_W + (tapn % 3) - (PAD_W + 1)) * C_IN;
      const int aoffn = tapn * 512 + kcn;
#pragma unroll
      for (int ii = 0; ii < 4; ++ii) {
        async16(aSrc + (size_t)ii * 8 * KTOT + aoffn, aDst + ii * 512);
        async16(Xt + (int)bOffs[ii] + toffn + kcn, bDst + ii * 512);
      }
    }
    // ---- dense bias fill, 2 rows per K-iter, hidden under the MFMA burst.
    // Stores from iter kk are drained by iter kk+1's syncthreads (compiler
    // emits vmcnt(0) before s_barrier), so they are globally ordered before
    // the epilogue scatter that may overwrite masked pixels in the span.
    if (kk < 64) {
#pragma unroll
      for (int rr2 = 0; rr2 < 2; ++rr2) {
        const int rr = kk * 2 + rr2;
        const float bv = bias[m0 + rr];
        float* o = out + (size_t)(m0 + rr) * HW;
        for (int p = lo_pix + tid; p < hi_pix; p += 256) o[p] = bv;
      }
    }
#pragma unroll
    for (int s = 0; s < 2; ++s)
#pragma unroll
      for (int i = 0; i < 4; ++i)
#pragma unroll
        for (int j = 0; j < 4; ++j)
          acc[i][j] = __builtin_amdgcn_mfma_f32_16x16x32_bf16(af[s][i], bfr[s][j],
                                                              acc[i][j], 0, 0, 0);
  }

  // epilogue: out[mrow][pix] = acc + bias   (C/D: col=lane&15, row=quad*4+r)
#pragma unroll
  for (int j = 0; j < 4; ++j) {
    const int pos = n0 + wn * 64 + j * 16 + col;
    if (pos < count) {
      const int n_pix = list[pos];
#pragma unroll
      for (int i = 0; i < 4; ++i) {
        const int mrow = m0 + wm * 64 + i * 16 + quad * 4;
        float* o = out + (size_t)mrow * HW + n_pix;
#pragma unroll
        for (int r = 0; r < 4; ++r)
          o[(size_t)r * HW] = acc[i][j][r] + bias[mrow + r];
      }
    }
  }
}

extern "C" void kernel_launch(void* const* d_in, const int* in_sizes, int n_in,
                              void* d_out, int out_size, void* d_ws, size_t ws_size,
                              hipStream_t stream) {
  const float* x    = (const float*)d_in[0];  // [512][192][192]
  const float* w    = (const float*)d_in[1];  // [512][512][3][3]
  const float* bias = (const float*)d_in[2];  // [512]
  const int*   mask = (const int*)d_in[3];    // [192][192]
  float* out = (float*)d_out;                 // [512][192][192]

  // ws layout: list (36864 int) | counter | counts[144] | pad | Xt | Wt
  int* list    = (int*)d_ws;
  int* counter = list + HW;
  int* counts  = counter + 1;
  ushort_t* Xt = (ushort_t*)((char*)d_ws + 148096);   // 128B-aligned
  ushort_t* Wt = Xt + (size_t)PAD_W * PAD_W * C_IN;

  prep_all<<<dim3(5969), 256, 0, stream>>>(x, w, mask, Xt, Wt, counts);
  compact_scatter<<<dim3(NCBLK), 256, 0, stream>>>(mask, counts, list, counter);
  conv_gemm<<<dim3((HW + 127) / 128, F_OUT / 128), 256, 0, stream>>>(
      Wt, Xt, bias, list, counter, out);
}